// Round 1
// baseline (3787.154 us; speedup 1.0000x reference)
//
#include <hip/hip_runtime.h>
#include <math.h>

#define N_NODES 50000
#define N_EDGES 800000
#define HID 128
#define LAT 64
#define IN_NODE 11
#define K_EDGE 261   // 2*HID + 1 + 4
#define TE 32        // edges (or nodes) per block tile
#define FST 36       // LDS row stride (32 + pad, multiple of 4 for float4)

__device__ __forceinline__ float elu_f(float v) { return v > 0.0f ? v : expm1f(v); }

// ---------------- radial: ||x[row]-x[col]||^2 per edge ----------------
__global__ void radial_kernel(const float* __restrict__ x, const int* __restrict__ edges,
                              float* __restrict__ radial) {
    int e = blockIdx.x * 256 + threadIdx.x;
    if (e >= N_EDGES) return;
    int r = edges[e], c = edges[N_EDGES + e];
    float dx = x[r*3+0] - x[c*3+0];
    float dy = x[r*3+1] - x[c*3+1];
    float dz = x[r*3+2] - x[c*3+2];
    radial[e] = dx*dx + dy*dy + dz*dz;
}

// ---------------- embedding: h = h0 @ emb_w + emb_b ----------------
__global__ void emb_kernel(const float* __restrict__ h0, const float* __restrict__ w,
                           const float* __restrict__ b, float* __restrict__ h) {
    int t = threadIdx.x;
    int n = blockIdx.x * 2 + (t >> 7);
    int c = t & 127;
    if (n >= N_NODES) return;
    float acc = b[c];
    #pragma unroll
    for (int k = 0; k < IN_NODE; ++k) acc += h0[n*IN_NODE + k] * w[k*HID + c];
    h[(size_t)n*HID + c] = acc;
}

// ---------------- fused edge MLP (2 layers) + atomic scatter ----------------
// Per block: 32 edges. LDS featT[k][e] transposed tile (261 x 36 pad) = 37.6KB.
// Phase1: t1 = elu(feat @ W1 + b1)  (K=261)
// Phase2: t2 = elu(t1 @ W2 + b2)    (K=128), atomicAdd into agg[row].
__global__ __launch_bounds__(256) void edge_fused_kernel(
    const float* __restrict__ h, const float* __restrict__ radial,
    const float* __restrict__ edge_attr, const int* __restrict__ edges,
    const float* __restrict__ w1, const float* __restrict__ b1,
    const float* __restrict__ w2, const float* __restrict__ b2,
    float* __restrict__ agg)
{
    __shared__ __align__(16) float featT[K_EDGE * FST];
    int t = threadIdx.x;
    int e0 = blockIdx.x * TE;

    // ---- stage gathered features, transposed: featT[k][e] ----
    {
        int el = t >> 3, j = t & 7;            // 8 threads per edge
        int e = e0 + el;
        int r = edges[e], c = edges[N_EDGES + e];
        const float4* hr = (const float4*)(h + (size_t)r * HID);
        const float4* hc = (const float4*)(h + (size_t)c * HID);
        #pragma unroll
        for (int q = 0; q < 4; ++q) {
            float4 v = hr[j*4 + q];
            float4 u = hc[j*4 + q];
            int k = j*16 + q*4;
            featT[(k+0)*FST + el] = v.x;
            featT[(k+1)*FST + el] = v.y;
            featT[(k+2)*FST + el] = v.z;
            featT[(k+3)*FST + el] = v.w;
            featT[(128+k+0)*FST + el] = u.x;
            featT[(128+k+1)*FST + el] = u.y;
            featT[(128+k+2)*FST + el] = u.z;
            featT[(128+k+3)*FST + el] = u.w;
        }
        if (j == 0) featT[256*FST + el] = radial[e];
        if (j < 4)  featT[(257+j)*FST + el] = edge_attr[(size_t)e*4 + j];
    }
    __syncthreads();

    int eg = t >> 5;           // 0..7 -> edges eg*4 .. eg*4+3
    int cg = (t & 31) << 2;    // cols cg .. cg+3
    float acc[4][4];
    #pragma unroll
    for (int i = 0; i < 4; ++i)
        #pragma unroll
        for (int j = 0; j < 4; ++j) acc[i][j] = 0.0f;

    // ---- phase 1 GEMM: K = 261 ----
    #pragma unroll 3
    for (int k = 0; k < K_EDGE; ++k) {
        float4 a4 = *(const float4*)&featT[k*FST + eg*4];
        float4 w4 = *(const float4*)&w1[(size_t)k*HID + cg];
        float av[4] = {a4.x, a4.y, a4.z, a4.w};
        float wv[4] = {w4.x, w4.y, w4.z, w4.w};
        #pragma unroll
        for (int i = 0; i < 4; ++i)
            #pragma unroll
            for (int j = 0; j < 4; ++j) acc[i][j] += av[i]*wv[j];
    }
    __syncthreads();

    // ---- epilogue 1: elu + bias, write t1 transposed back into featT ----
    {
        float4 b1v = *(const float4*)&b1[cg];
        float bb[4] = {b1v.x, b1v.y, b1v.z, b1v.w};
        #pragma unroll
        for (int j = 0; j < 4; ++j) {
            float4 v;
            v.x = elu_f(acc[0][j] + bb[j]);
            v.y = elu_f(acc[1][j] + bb[j]);
            v.z = elu_f(acc[2][j] + bb[j]);
            v.w = elu_f(acc[3][j] + bb[j]);
            *(float4*)&featT[(cg+j)*FST + eg*4] = v;
        }
    }
    __syncthreads();

    #pragma unroll
    for (int i = 0; i < 4; ++i)
        #pragma unroll
        for (int j = 0; j < 4; ++j) acc[i][j] = 0.0f;

    // ---- phase 2 GEMM: K = 128 ----
    #pragma unroll 4
    for (int k = 0; k < HID; ++k) {
        float4 a4 = *(const float4*)&featT[k*FST + eg*4];
        float4 w4 = *(const float4*)&w2[(size_t)k*HID + cg];
        float av[4] = {a4.x, a4.y, a4.z, a4.w};
        float wv[4] = {w4.x, w4.y, w4.z, w4.w};
        #pragma unroll
        for (int i = 0; i < 4; ++i)
            #pragma unroll
            for (int j = 0; j < 4; ++j) acc[i][j] += av[i]*wv[j];
    }

    // ---- epilogue 2: elu + bias, atomic scatter-add to agg[row] ----
    float4 b2v = *(const float4*)&b2[cg];
    float b2a[4] = {b2v.x, b2v.y, b2v.z, b2v.w};
    #pragma unroll
    for (int i = 0; i < 4; ++i) {
        int e = e0 + eg*4 + i;
        int r = edges[e];
        float* dst = agg + (size_t)r * HID + cg;
        #pragma unroll
        for (int j = 0; j < 4; ++j) atomicAdd(dst + j, elu_f(acc[i][j] + b2a[j]));
    }
}

// ---------------- fused node MLP (2 layers) ----------------
// concat(h, agg, h) @ W1 = h @ (W1[0:128]+W1[256:384]) + agg @ W1[128:256]
__global__ __launch_bounds__(256) void node_fused_kernel(
    const float* __restrict__ h, const float* __restrict__ agg,
    const float* __restrict__ w1, const float* __restrict__ b1,
    const float* __restrict__ w2, const float* __restrict__ b2,
    float* __restrict__ hout)
{
    __shared__ __align__(16) float hT[HID * FST];
    __shared__ __align__(16) float aT[HID * FST];
    int t = threadIdx.x;
    int n0 = blockIdx.x * TE;

    {
        int nl = t >> 3, j = t & 7;
        int n = n0 + nl;
        int idx = n < N_NODES ? n : N_NODES - 1;
        const float4* hp = (const float4*)(h   + (size_t)idx * HID);
        const float4* ap = (const float4*)(agg + (size_t)idx * HID);
        #pragma unroll
        for (int q = 0; q < 4; ++q) {
            float4 v = hp[j*4 + q];
            float4 u = ap[j*4 + q];
            int k = j*16 + q*4;
            hT[(k+0)*FST + nl] = v.x; hT[(k+1)*FST + nl] = v.y;
            hT[(k+2)*FST + nl] = v.z; hT[(k+3)*FST + nl] = v.w;
            aT[(k+0)*FST + nl] = u.x; aT[(k+1)*FST + nl] = u.y;
            aT[(k+2)*FST + nl] = u.z; aT[(k+3)*FST + nl] = u.w;
        }
    }
    __syncthreads();

    int ng = t >> 5;
    int cg = (t & 31) << 2;
    float acc[4][4];
    #pragma unroll
    for (int i = 0; i < 4; ++i)
        #pragma unroll
        for (int j = 0; j < 4; ++j) acc[i][j] = 0.0f;

    #pragma unroll 2
    for (int k = 0; k < HID; ++k) {
        float4 a1 = *(const float4*)&hT[k*FST + ng*4];
        float4 a2 = *(const float4*)&aT[k*FST + ng*4];
        float4 wx = *(const float4*)&w1[(size_t)k*HID + cg];
        float4 wz = *(const float4*)&w1[(size_t)(256+k)*HID + cg];
        float4 wy = *(const float4*)&w1[(size_t)(128+k)*HID + cg];
        float wA[4] = {wx.x+wz.x, wx.y+wz.y, wx.z+wz.z, wx.w+wz.w};
        float wB[4] = {wy.x, wy.y, wy.z, wy.w};
        float av[4] = {a1.x, a1.y, a1.z, a1.w};
        float uv[4] = {a2.x, a2.y, a2.z, a2.w};
        #pragma unroll
        for (int i = 0; i < 4; ++i)
            #pragma unroll
            for (int j = 0; j < 4; ++j) acc[i][j] += av[i]*wA[j] + uv[i]*wB[j];
    }
    __syncthreads();

    {
        float4 b1v = *(const float4*)&b1[cg];
        float bb[4] = {b1v.x, b1v.y, b1v.z, b1v.w};
        #pragma unroll
        for (int j = 0; j < 4; ++j) {
            float4 v;
            v.x = elu_f(acc[0][j] + bb[j]);
            v.y = elu_f(acc[1][j] + bb[j]);
            v.z = elu_f(acc[2][j] + bb[j]);
            v.w = elu_f(acc[3][j] + bb[j]);
            *(float4*)&hT[(cg+j)*FST + ng*4] = v;
        }
    }
    __syncthreads();

    #pragma unroll
    for (int i = 0; i < 4; ++i)
        #pragma unroll
        for (int j = 0; j < 4; ++j) acc[i][j] = 0.0f;

    #pragma unroll 4
    for (int k = 0; k < HID; ++k) {
        float4 a4 = *(const float4*)&hT[k*FST + ng*4];
        float4 w4 = *(const float4*)&w2[(size_t)k*HID + cg];
        float av[4] = {a4.x, a4.y, a4.z, a4.w};
        float wv[4] = {w4.x, w4.y, w4.z, w4.w};
        #pragma unroll
        for (int i = 0; i < 4; ++i)
            #pragma unroll
            for (int j = 0; j < 4; ++j) acc[i][j] += av[i]*wv[j];
    }

    float4 b2v = *(const float4*)&b2[cg];
    float b2a[4] = {b2v.x, b2v.y, b2v.z, b2v.w};
    #pragma unroll
    for (int i = 0; i < 4; ++i) {
        int n = n0 + ng*4 + i;
        if (n < N_NODES) {
            float4 v;
            v.x = acc[i][0] + b2a[0];
            v.y = acc[i][1] + b2a[1];
            v.z = acc[i][2] + b2a[2];
            v.w = acc[i][3] + b2a[3];
            *(float4*)&hout[(size_t)n*HID + cg] = v;   // no activation on layer output
        }
    }
}

// ---------------- output head: z = mu + 0.01*eps*exp(0.5*logvar) ----------------
__global__ void out_kernel(const float* __restrict__ h, const float* __restrict__ label,
                           const float* __restrict__ eps,
                           const float* __restrict__ mu_w, const float* __restrict__ mu_b,
                           const float* __restrict__ var_w, const float* __restrict__ var_b,
                           float* __restrict__ z)
{
    int t = threadIdx.x;
    int n = blockIdx.x * 4 + (t >> 6);
    int c = t & 63;
    if (n >= N_NODES) return;
    float am = mu_b[c], av = var_b[c];
    #pragma unroll 4
    for (int k = 0; k < HID; ++k) {
        float hv = h[(size_t)n*HID + k];
        am += hv * mu_w[k*LAT + c];
        av += hv * var_w[k*LAT + c];
    }
    #pragma unroll
    for (int k = 0; k < 7; ++k) {
        float lv = label[(size_t)n*7 + k];
        am += lv * mu_w[(HID+k)*LAT + c];
        av += lv * var_w[(HID+k)*LAT + c];
    }
    float sd = expf(av * 0.5f);
    z[(size_t)n*LAT + c] = am + 0.01f * eps[(size_t)n*LAT + c] * sd;
}

extern "C" void kernel_launch(void* const* d_in, const int* in_sizes, int n_in,
                              void* d_out, int out_size, void* d_ws, size_t ws_size,
                              hipStream_t stream) {
    const float* h0        = (const float*)d_in[0];
    const float* label     = (const float*)d_in[1];
    const float* x         = (const float*)d_in[2];
    const float* edge_attr = (const float*)d_in[3];
    const float* eps       = (const float*)d_in[4];
    const float* emb_w     = (const float*)d_in[5];
    const float* emb_b     = (const float*)d_in[6];
    const float* edge_w1   = (const float*)d_in[7];
    const float* edge_b1   = (const float*)d_in[8];
    const float* edge_w2   = (const float*)d_in[9];
    const float* edge_b2   = (const float*)d_in[10];
    const float* node_w1   = (const float*)d_in[11];
    const float* node_b1   = (const float*)d_in[12];
    const float* node_w2   = (const float*)d_in[13];
    const float* node_b2   = (const float*)d_in[14];
    const float* mu_w      = (const float*)d_in[15];
    const float* mu_b      = (const float*)d_in[16];
    const float* var_w     = (const float*)d_in[17];
    const float* var_b     = (const float*)d_in[18];
    const int*   edges     = (const int*)d_in[19];
    float* out = (float*)d_out;

    float* hA     = (float*)d_ws;                 // N*128
    float* hB     = hA + (size_t)N_NODES * HID;   // N*128
    float* agg    = hB + (size_t)N_NODES * HID;   // N*128
    float* radial = agg + (size_t)N_NODES * HID;  // E

    radial_kernel<<<(N_EDGES + 255) / 256, 256, 0, stream>>>(x, edges, radial);
    emb_kernel<<<N_NODES / 2, 256, 0, stream>>>(h0, emb_w, emb_b, hA);

    const float* hcur = hA;
    float* hnext = hB;
    for (int l = 0; l < 2; ++l) {
        hipMemsetAsync(agg, 0, (size_t)N_NODES * HID * sizeof(float), stream);
        edge_fused_kernel<<<N_EDGES / TE, 256, 0, stream>>>(
            hcur, radial, edge_attr, edges,
            edge_w1 + (size_t)l * K_EDGE * HID, edge_b1 + l * HID,
            edge_w2 + (size_t)l * HID * HID,   edge_b2 + l * HID, agg);
        node_fused_kernel<<<(N_NODES + TE - 1) / TE, 256, 0, stream>>>(
            hcur, agg,
            node_w1 + (size_t)l * 384 * HID, node_b1 + l * HID,
            node_w2 + (size_t)l * HID * HID, node_b2 + l * HID, hnext);
        float* tmp = (float*)hcur; hcur = hnext; hnext = tmp;
    }

    out_kernel<<<N_NODES / 4, 256, 0, stream>>>(hcur, label, eps, mu_w, mu_b,
                                                var_w, var_b, out);
}

// Round 2
// 3061.022 us; speedup vs baseline: 1.2372x; 1.2372x over previous
//
#include <hip/hip_runtime.h>
#include <math.h>

#define N_NODES 50000
#define N_EDGES 800000
#define HID 128
#define LAT 64
#define IN_NODE 11
#define K_EDGE 261    // 2*HID + 1 + 4
#define KP1 288       // K_EDGE padded to multiple of 32
#define KN 256        // node MLP folded K (h + agg)
#define AST 296       // edge feature LDS row stride (bf16 elems), 288+8 pad
#define NST 264       // node feature LDS row stride, 256+8 pad
#define TST 136       // t1 LDS row stride, 128+8 pad

typedef __attribute__((ext_vector_type(8))) short short8;
typedef __attribute__((ext_vector_type(4))) short short4v;
typedef __attribute__((ext_vector_type(4))) float floatx4;

__device__ __forceinline__ float elu_f(float v) { return v > 0.0f ? v : expm1f(v); }

__device__ __forceinline__ short f2bf(float f) {
    unsigned int u = __builtin_bit_cast(unsigned int, f);
    u += 0x7fffu + ((u >> 16) & 1u);   // round-to-nearest-even
    return (short)(u >> 16);
}

// ---------------- radial: ||x[row]-x[col]||^2 per edge ----------------
__global__ void radial_kernel(const float* __restrict__ x, const int* __restrict__ edges,
                              float* __restrict__ radial) {
    int e = blockIdx.x * 256 + threadIdx.x;
    if (e >= N_EDGES) return;
    int r = edges[e], c = edges[N_EDGES + e];
    float dx = x[r*3+0] - x[c*3+0];
    float dy = x[r*3+1] - x[c*3+1];
    float dz = x[r*3+2] - x[c*3+2];
    radial[e] = dx*dx + dy*dy + dz*dz;
}

// ---------------- embedding: h = h0 @ emb_w + emb_b ----------------
__global__ void emb_kernel(const float* __restrict__ h0, const float* __restrict__ w,
                           const float* __restrict__ b, float* __restrict__ h) {
    int t = threadIdx.x;
    int n = blockIdx.x * 2 + (t >> 7);
    int c = t & 127;
    if (n >= N_NODES) return;
    float acc = b[c];
    #pragma unroll
    for (int k = 0; k < IN_NODE; ++k) acc += h0[n*IN_NODE + k] * w[k*HID + c];
    h[(size_t)n*HID + c] = acc;
}

// ---------------- weight prep: transpose + bf16 + pad/fold ----------------
// ew1T: [2][128][288] (zero-padded K)   ew2T: [2][128][128]
// nw1T: [2][128][256] (h-weights folded: W1a+W1c, then W1b)   nw2T: [2][128][128]
__global__ void prep_weights(const float* __restrict__ ew1, const float* __restrict__ ew2,
                             const float* __restrict__ nw1, const float* __restrict__ nw2,
                             short* __restrict__ ew1T, short* __restrict__ ew2T,
                             short* __restrict__ nw1T, short* __restrict__ nw2T) {
    int idx = blockIdx.x * 256 + threadIdx.x;
    int stride = gridDim.x * 256;
    for (int i = idx; i < 2*128*KP1; i += stride) {
        int l = i / (128*KP1); int r = i % (128*KP1);
        int c = r / KP1; int k = r % KP1;
        float v = (k < K_EDGE) ? ew1[(size_t)l*K_EDGE*128 + (size_t)k*128 + c] : 0.0f;
        ew1T[i] = f2bf(v);
    }
    for (int i = idx; i < 2*128*128; i += stride) {
        int l = i / (128*128); int r = i % (128*128);
        int c = r / 128; int k = r % 128;
        ew2T[i] = f2bf(ew2[(size_t)l*128*128 + (size_t)k*128 + c]);
    }
    for (int i = idx; i < 2*128*KN; i += stride) {
        int l = i / (128*KN); int r = i % (128*KN);
        int c = r / KN; int k = r % KN;
        const float* base = nw1 + (size_t)l*384*128;
        float v = (k < 128) ? (base[(size_t)k*128 + c] + base[(size_t)(256+k)*128 + c])
                            : base[(size_t)k*128 + c];
        nw1T[i] = f2bf(v);
    }
    for (int i = idx; i < 2*128*128; i += stride) {
        int l = i / (128*128); int r = i % (128*128);
        int c = r / 128; int k = r % 128;
        nw2T[i] = f2bf(nw2[(size_t)l*128*128 + (size_t)k*128 + c]);
    }
}

// ---------------- MFMA edge MLP (2 layers) + atomic scatter ----------------
// Per block: 32 edges, 256 threads = 4 waves. Orientation: D[c][e] = W^T · feat
// so A = transposed weights (global, k-contiguous), B = features (LDS, k-contiguous).
// C-frag: col(lane&15)=edge, row(quad*4+reg)=channel -> contiguous channel packs.
__global__ __launch_bounds__(256) void edge_mfma_kernel(
    const float* __restrict__ h, const float* __restrict__ radial,
    const float* __restrict__ edge_attr, const int* __restrict__ edges,
    const short* __restrict__ w1T, const float* __restrict__ b1,
    const short* __restrict__ w2T, const float* __restrict__ b2,
    float* __restrict__ agg)
{
    __shared__ short featA[32 * AST];   // 18944 B
    __shared__ short t1[32 * TST];      // 8704 B
    int t = threadIdx.x;
    int e0 = blockIdx.x * 32;

    // ---- stage gathered features as bf16, row-major [edge][k] ----
    {
        int el = t >> 3, j = t & 7;               // 8 threads per edge, 16 cols each
        int e = e0 + el;
        int r = edges[e], c = edges[N_EDGES + e];
        const float4* hr = (const float4*)(h + (size_t)r * HID) + j*4;
        const float4* hc = (const float4*)(h + (size_t)c * HID) + j*4;
        float4 v0 = hr[0], v1 = hr[1], v2 = hr[2], v3 = hr[3];
        float4 u0 = hc[0], u1 = hc[1], u2 = hc[2], u3 = hc[3];
        short8 s0 = { f2bf(v0.x), f2bf(v0.y), f2bf(v0.z), f2bf(v0.w),
                      f2bf(v1.x), f2bf(v1.y), f2bf(v1.z), f2bf(v1.w) };
        short8 s1 = { f2bf(v2.x), f2bf(v2.y), f2bf(v2.z), f2bf(v2.w),
                      f2bf(v3.x), f2bf(v3.y), f2bf(v3.z), f2bf(v3.w) };
        short8 s2 = { f2bf(u0.x), f2bf(u0.y), f2bf(u0.z), f2bf(u0.w),
                      f2bf(u1.x), f2bf(u1.y), f2bf(u1.z), f2bf(u1.w) };
        short8 s3 = { f2bf(u2.x), f2bf(u2.y), f2bf(u2.z), f2bf(u2.w),
                      f2bf(u3.x), f2bf(u3.y), f2bf(u3.z), f2bf(u3.w) };
        *(short8*)&featA[el*AST + j*16]       = s0;
        *(short8*)&featA[el*AST + j*16 + 8]   = s1;
        *(short8*)&featA[el*AST + 128 + j*16]     = s2;
        *(short8*)&featA[el*AST + 128 + j*16 + 8] = s3;
    }
    if (t < 32) {  // tail: radial, edge_attr, zero pad to 288
        int e = e0 + t;
        float4 ea = *(const float4*)(edge_attr + (size_t)e*4);
        short8 s = { f2bf(radial[e]), f2bf(ea.x), f2bf(ea.y), f2bf(ea.z), f2bf(ea.w),
                     0, 0, 0 };
        short8 z = {0,0,0,0,0,0,0,0};
        *(short8*)&featA[t*AST + 256] = s;
        *(short8*)&featA[t*AST + 264] = z;
        *(short8*)&featA[t*AST + 272] = z;
        *(short8*)&featA[t*AST + 280] = z;
    }
    __syncthreads();

    int lane = t & 63;
    int wv = t >> 6;          // wave: channel block c in [wv*32, wv*32+32)
    int l15 = lane & 15;
    int quad = lane >> 4;

    int r0 = edges[e0 + l15];
    int r1 = edges[e0 + 16 + l15];

    floatx4 acc[2][2] = {{{0,0,0,0},{0,0,0,0}},{{0,0,0,0},{0,0,0,0}}};

    // ---- layer 1: K = 288 ----
    #pragma unroll
    for (int ks = 0; ks < KP1/32; ++ks) {
        int koff = ks*32 + quad*8;
        short8 a0 = *(const short8*)&w1T[(size_t)(wv*32 + l15)*KP1 + koff];
        short8 a1 = *(const short8*)&w1T[(size_t)(wv*32 + 16 + l15)*KP1 + koff];
        short8 bb0 = *(const short8*)&featA[l15*AST + koff];
        short8 bb1 = *(const short8*)&featA[(16 + l15)*AST + koff];
        acc[0][0] = __builtin_amdgcn_mfma_f32_16x16x32_bf16(a0, bb0, acc[0][0], 0, 0, 0);
        acc[0][1] = __builtin_amdgcn_mfma_f32_16x16x32_bf16(a0, bb1, acc[0][1], 0, 0, 0);
        acc[1][0] = __builtin_amdgcn_mfma_f32_16x16x32_bf16(a1, bb0, acc[1][0], 0, 0, 0);
        acc[1][1] = __builtin_amdgcn_mfma_f32_16x16x32_bf16(a1, bb1, acc[1][1], 0, 0, 0);
    }

    // ---- epilogue 1: bias + elu, pack 4 channels -> 8B LDS write t1[e][c] ----
    #pragma unroll
    for (int mi = 0; mi < 2; ++mi) {
        int cb = wv*32 + mi*16 + quad*4;
        float g0 = b1[cb], g1 = b1[cb+1], g2 = b1[cb+2], g3 = b1[cb+3];
        #pragma unroll
        for (int ni = 0; ni < 2; ++ni) {
            short4v s = { f2bf(elu_f(acc[mi][ni][0] + g0)),
                          f2bf(elu_f(acc[mi][ni][1] + g1)),
                          f2bf(elu_f(acc[mi][ni][2] + g2)),
                          f2bf(elu_f(acc[mi][ni][3] + g3)) };
            *(short4v*)&t1[(ni*16 + l15)*TST + cb] = s;
        }
    }
    __syncthreads();

    floatx4 acc2[2][2] = {{{0,0,0,0},{0,0,0,0}},{{0,0,0,0},{0,0,0,0}}};

    // ---- layer 2: K = 128 ----
    #pragma unroll
    for (int ks = 0; ks < 4; ++ks) {
        int koff = ks*32 + quad*8;
        short8 a0 = *(const short8*)&w2T[(size_t)(wv*32 + l15)*128 + koff];
        short8 a1 = *(const short8*)&w2T[(size_t)(wv*32 + 16 + l15)*128 + koff];
        short8 bb0 = *(const short8*)&t1[l15*TST + koff];
        short8 bb1 = *(const short8*)&t1[(16 + l15)*TST + koff];
        acc2[0][0] = __builtin_amdgcn_mfma_f32_16x16x32_bf16(a0, bb0, acc2[0][0], 0, 0, 0);
        acc2[0][1] = __builtin_amdgcn_mfma_f32_16x16x32_bf16(a0, bb1, acc2[0][1], 0, 0, 0);
        acc2[1][0] = __builtin_amdgcn_mfma_f32_16x16x32_bf16(a1, bb0, acc2[1][0], 0, 0, 0);
        acc2[1][1] = __builtin_amdgcn_mfma_f32_16x16x32_bf16(a1, bb1, acc2[1][1], 0, 0, 0);
    }

    // ---- epilogue 2: bias + elu + atomic scatter-add to agg[row] ----
    #pragma unroll
    for (int mi = 0; mi < 2; ++mi) {
        int cb = wv*32 + mi*16 + quad*4;
        float g0 = b2[cb], g1 = b2[cb+1], g2 = b2[cb+2], g3 = b2[cb+3];
        #pragma unroll
        for (int ni = 0; ni < 2; ++ni) {
            int row = ni ? r1 : r0;
            float* dst = agg + (size_t)row * HID + cb;
            atomicAdd(dst + 0, elu_f(acc2[mi][ni][0] + g0));
            atomicAdd(dst + 1, elu_f(acc2[mi][ni][1] + g1));
            atomicAdd(dst + 2, elu_f(acc2[mi][ni][2] + g2));
            atomicAdd(dst + 3, elu_f(acc2[mi][ni][3] + g3));
        }
    }
}

// ---------------- MFMA node MLP (2 layers), in-place h update ----------------
__global__ __launch_bounds__(256) void node_mfma_kernel(
    const float* __restrict__ h, const float* __restrict__ agg,
    const short* __restrict__ w1T, const float* __restrict__ b1,
    const short* __restrict__ w2T, const float* __restrict__ b2,
    float* __restrict__ hout)
{
    __shared__ short featN[32 * NST];   // 16896 B
    __shared__ short t1[32 * TST];      // 8704 B
    int t = threadIdx.x;
    int n0 = blockIdx.x * 32;

    {
        int nl = t >> 3, j = t & 7;
        int n = n0 + nl;
        int idx = n < N_NODES ? n : N_NODES - 1;
        const float4* hp = (const float4*)(h   + (size_t)idx * HID) + j*4;
        const float4* ap = (const float4*)(agg + (size_t)idx * HID) + j*4;
        float4 v0 = hp[0], v1 = hp[1], v2 = hp[2], v3 = hp[3];
        float4 u0 = ap[0], u1 = ap[1], u2 = ap[2], u3 = ap[3];
        short8 s0 = { f2bf(v0.x), f2bf(v0.y), f2bf(v0.z), f2bf(v0.w),
                      f2bf(v1.x), f2bf(v1.y), f2bf(v1.z), f2bf(v1.w) };
        short8 s1 = { f2bf(v2.x), f2bf(v2.y), f2bf(v2.z), f2bf(v2.w),
                      f2bf(v3.x), f2bf(v3.y), f2bf(v3.z), f2bf(v3.w) };
        short8 s2 = { f2bf(u0.x), f2bf(u0.y), f2bf(u0.z), f2bf(u0.w),
                      f2bf(u1.x), f2bf(u1.y), f2bf(u1.z), f2bf(u1.w) };
        short8 s3 = { f2bf(u2.x), f2bf(u2.y), f2bf(u2.z), f2bf(u2.w),
                      f2bf(u3.x), f2bf(u3.y), f2bf(u3.z), f2bf(u3.w) };
        *(short8*)&featN[nl*NST + j*16]       = s0;
        *(short8*)&featN[nl*NST + j*16 + 8]   = s1;
        *(short8*)&featN[nl*NST + 128 + j*16]     = s2;
        *(short8*)&featN[nl*NST + 128 + j*16 + 8] = s3;
    }
    __syncthreads();

    int lane = t & 63;
    int wv = t >> 6;
    int l15 = lane & 15;
    int quad = lane >> 4;

    floatx4 acc[2][2] = {{{0,0,0,0},{0,0,0,0}},{{0,0,0,0},{0,0,0,0}}};

    #pragma unroll
    for (int ks = 0; ks < KN/32; ++ks) {
        int koff = ks*32 + quad*8;
        short8 a0 = *(const short8*)&w1T[(size_t)(wv*32 + l15)*KN + koff];
        short8 a1 = *(const short8*)&w1T[(size_t)(wv*32 + 16 + l15)*KN + koff];
        short8 bb0 = *(const short8*)&featN[l15*NST + koff];
        short8 bb1 = *(const short8*)&featN[(16 + l15)*NST + koff];
        acc[0][0] = __builtin_amdgcn_mfma_f32_16x16x32_bf16(a0, bb0, acc[0][0], 0, 0, 0);
        acc[0][1] = __builtin_amdgcn_mfma_f32_16x16x32_bf16(a0, bb1, acc[0][1], 0, 0, 0);
        acc[1][0] = __builtin_amdgcn_mfma_f32_16x16x32_bf16(a1, bb0, acc[1][0], 0, 0, 0);
        acc[1][1] = __builtin_amdgcn_mfma_f32_16x16x32_bf16(a1, bb1, acc[1][1], 0, 0, 0);
    }

    #pragma unroll
    for (int mi = 0; mi < 2; ++mi) {
        int cb = wv*32 + mi*16 + quad*4;
        float g0 = b1[cb], g1 = b1[cb+1], g2 = b1[cb+2], g3 = b1[cb+3];
        #pragma unroll
        for (int ni = 0; ni < 2; ++ni) {
            short4v s = { f2bf(elu_f(acc[mi][ni][0] + g0)),
                          f2bf(elu_f(acc[mi][ni][1] + g1)),
                          f2bf(elu_f(acc[mi][ni][2] + g2)),
                          f2bf(elu_f(acc[mi][ni][3] + g3)) };
            *(short4v*)&t1[(ni*16 + l15)*TST + cb] = s;
        }
    }
    __syncthreads();

    floatx4 acc2[2][2] = {{{0,0,0,0},{0,0,0,0}},{{0,0,0,0},{0,0,0,0}}};

    #pragma unroll
    for (int ks = 0; ks < 4; ++ks) {
        int koff = ks*32 + quad*8;
        short8 a0 = *(const short8*)&w2T[(size_t)(wv*32 + l15)*128 + koff];
        short8 a1 = *(const short8*)&w2T[(size_t)(wv*32 + 16 + l15)*128 + koff];
        short8 bb0 = *(const short8*)&t1[l15*TST + koff];
        short8 bb1 = *(const short8*)&t1[(16 + l15)*TST + koff];
        acc2[0][0] = __builtin_amdgcn_mfma_f32_16x16x32_bf16(a0, bb0, acc2[0][0], 0, 0, 0);
        acc2[0][1] = __builtin_amdgcn_mfma_f32_16x16x32_bf16(a0, bb1, acc2[0][1], 0, 0, 0);
        acc2[1][0] = __builtin_amdgcn_mfma_f32_16x16x32_bf16(a1, bb0, acc2[1][0], 0, 0, 0);
        acc2[1][1] = __builtin_amdgcn_mfma_f32_16x16x32_bf16(a1, bb1, acc2[1][1], 0, 0, 0);
    }

    #pragma unroll
    for (int mi = 0; mi < 2; ++mi) {
        int cb = wv*32 + mi*16 + quad*4;
        float g0 = b2[cb], g1 = b2[cb+1], g2 = b2[cb+2], g3 = b2[cb+3];
        #pragma unroll
        for (int ni = 0; ni < 2; ++ni) {
            int n = n0 + ni*16 + l15;
            if (n < N_NODES) {
                float4 v = { acc2[mi][ni][0] + g0, acc2[mi][ni][1] + g1,
                             acc2[mi][ni][2] + g2, acc2[mi][ni][3] + g3 };
                *(float4*)&hout[(size_t)n*HID + cb] = v;   // no activation on layer out
            }
        }
    }
}

// ---------------- output head: z = mu + 0.01*eps*exp(0.5*logvar) ----------------
__global__ void out_kernel(const float* __restrict__ h, const float* __restrict__ label,
                           const float* __restrict__ eps,
                           const float* __restrict__ mu_w, const float* __restrict__ mu_b,
                           const float* __restrict__ var_w, const float* __restrict__ var_b,
                           float* __restrict__ z)
{
    int t = threadIdx.x;
    int n = blockIdx.x * 4 + (t >> 6);
    int c = t & 63;
    if (n >= N_NODES) return;
    float am = mu_b[c], av = var_b[c];
    #pragma unroll 4
    for (int k = 0; k < HID; ++k) {
        float hv = h[(size_t)n*HID + k];
        am += hv * mu_w[k*LAT + c];
        av += hv * var_w[k*LAT + c];
    }
    #pragma unroll
    for (int k = 0; k < 7; ++k) {
        float lv = label[(size_t)n*7 + k];
        am += lv * mu_w[(HID+k)*LAT + c];
        av += lv * var_w[(HID+k)*LAT + c];
    }
    float sd = expf(av * 0.5f);
    z[(size_t)n*LAT + c] = am + 0.01f * eps[(size_t)n*LAT + c] * sd;
}

extern "C" void kernel_launch(void* const* d_in, const int* in_sizes, int n_in,
                              void* d_out, int out_size, void* d_ws, size_t ws_size,
                              hipStream_t stream) {
    const float* h0        = (const float*)d_in[0];
    const float* label     = (const float*)d_in[1];
    const float* x         = (const float*)d_in[2];
    const float* edge_attr = (const float*)d_in[3];
    const float* eps       = (const float*)d_in[4];
    const float* emb_w     = (const float*)d_in[5];
    const float* emb_b     = (const float*)d_in[6];
    const float* edge_w1   = (const float*)d_in[7];
    const float* edge_b1   = (const float*)d_in[8];
    const float* edge_w2   = (const float*)d_in[9];
    const float* edge_b2   = (const float*)d_in[10];
    const float* node_w1   = (const float*)d_in[11];
    const float* node_b1   = (const float*)d_in[12];
    const float* node_w2   = (const float*)d_in[13];
    const float* node_b2   = (const float*)d_in[14];
    const float* mu_w      = (const float*)d_in[15];
    const float* mu_b      = (const float*)d_in[16];
    const float* var_w     = (const float*)d_in[17];
    const float* var_b     = (const float*)d_in[18];
    const int*   edges     = (const int*)d_in[19];
    float* out = (float*)d_out;

    float* hA     = (float*)d_ws;                  // N*128 f32
    float* agg    = hA + (size_t)N_NODES * HID;    // N*128 f32
    float* radial = agg + (size_t)N_NODES * HID;   // E f32
    short* ew1T   = (short*)(radial + N_EDGES);    // 2*128*288
    short* ew2T   = ew1T + 2*128*KP1;              // 2*128*128
    short* nw1T   = ew2T + 2*128*128;              // 2*128*256
    short* nw2T   = nw1T + 2*128*KN;               // 2*128*128

    prep_weights<<<200, 256, 0, stream>>>(edge_w1, edge_w2, node_w1, node_w2,
                                          ew1T, ew2T, nw1T, nw2T);
    radial_kernel<<<(N_EDGES + 255) / 256, 256, 0, stream>>>(x, edges, radial);
    emb_kernel<<<N_NODES / 2, 256, 0, stream>>>(h0, emb_w, emb_b, hA);

    for (int l = 0; l < 2; ++l) {
        hipMemsetAsync(agg, 0, (size_t)N_NODES * HID * sizeof(float), stream);
        edge_mfma_kernel<<<N_EDGES / 32, 256, 0, stream>>>(
            hA, radial, edge_attr, edges,
            ew1T + (size_t)l * 128 * KP1, edge_b1 + l * HID,
            ew2T + (size_t)l * 128 * 128, edge_b2 + l * HID, agg);
        node_mfma_kernel<<<(N_NODES + 31) / 32, 256, 0, stream>>>(
            hA, agg,
            nw1T + (size_t)l * 128 * KN, node_b1 + l * HID,
            nw2T + (size_t)l * 128 * 128, node_b2 + l * HID, hA);
    }

    out_kernel<<<N_NODES / 4, 256, 0, stream>>>(hA, label, eps, mu_w, mu_b,
                                                var_w, var_b, out);
}